// Round 3
// baseline (797.662 us; speedup 1.0000x reference)
//
#include <hip/hip_runtime.h>

// Problem constants (from reference):
//   B=256, C=8, M=16, N=4096, R=D=64, CM=C*M=128
//   outputs[b,n] = sum_cm x[b,cm,n] * w[cm]          (512 MiB in, 4 MiB out)
//   idx = argmax_n outputs[b,:]  (first-max tiebreak)
//   r = trunc(r_target[idx/64]); d = trunc(d_target[idx%64])
//   flat out = [outputs (B*N), d (B), r (B), d (B)]
//
// R3: DIAGNOSTIC A/B ROUND. Three structurally different kernels (R0/R1/R2)
// all produced identical ~310-340 us implied kernel time (~1.65 TB/s) --
// schedule-insensitive, and our dispatch never appears in the top-5 profile
// (cutoff = the ~330 us harness fills), so we have never seen its counters.
// This round launches the SAME conv kernel TWICE (idempotent: both instances
// write identical values), differing only in the one invariant left:
// nontemporal vs plain loads. Both dispatches get profiled independently;
// whichever is slow lands in the top-5 WITH its FETCH_SIZE / VGPR /
// Occupancy counters, resolving traffic-amplification vs issue-bound
// definitively. If nt was the killer, this round is even a net win.

#define BATCH   256
#define NDIM    4096
#define CM      128
#define SLICES  4
#define SLICE_COLS (NDIM / SLICES)      // 1024
#define THREADS1   (SLICE_COLS / 4)     // 256 threads, 4 cols each
#define NWAVES1    (THREADS1 / 64)      // 4
#define GROUP   8
#define NGROUPS (CM / GROUP)            // 16

typedef float v4f __attribute__((ext_vector_type(4)));

template<bool NT>
__global__ __launch_bounds__(THREADS1) void conv_partial_kernel(
    const float* __restrict__ x, const float* __restrict__ W,
    float* __restrict__ out, float2* __restrict__ partial)
{
    __shared__ float w[CM];
    __shared__ float sval[NWAVES1];
    __shared__ int   sidx[NWAVES1];

    const int blk = blockIdx.x;
    const int b   = blk >> 2;           // / SLICES
    const int s   = blk & (SLICES - 1);
    const int tid = threadIdx.x;

    if (tid < CM) w[tid] = W[tid];
    __syncthreads();

    const int n0 = s * SLICE_COLS + tid * 4;        // this thread's 4 columns
    const float* xp = x + (size_t)b * (CM * NDIM) + n0;

    float acc0 = 0.f, acc1 = 0.f, acc2 = 0.f, acc3 = 0.f;

    #pragma unroll 1
    for (int g = 0; g < NGROUPS; ++g) {
        v4f v[GROUP];
        #pragma unroll
        for (int j = 0; j < GROUP; ++j) {
            const v4f* p = (const v4f*)(xp + (size_t)(g * GROUP + j) * NDIM);
            if constexpr (NT) {
                v[j] = __builtin_nontemporal_load(p);
            } else {
                v[j] = *p;                           // plain global_load_dwordx4
            }
        }
        #pragma unroll
        for (int j = 0; j < GROUP; ++j) {
            const float wc = w[g * GROUP + j];      // uniform ds_read broadcast
            acc0 += v[j].x * wc;
            acc1 += v[j].y * wc;
            acc2 += v[j].z * wc;
            acc3 += v[j].w * wc;
        }
    }

    // Plain store both ways (4 MiB total -- not the variable under test).
    *(float4*)(out + (size_t)b * NDIM + n0) = make_float4(acc0, acc1, acc2, acc3);

    // Thread-local argmax (ascending index => first-occurrence tiebreak).
    float bv = acc0; int bi = n0;
    if (acc1 > bv) { bv = acc1; bi = n0 + 1; }
    if (acc2 > bv) { bv = acc2; bi = n0 + 2; }
    if (acc3 > bv) { bv = acc3; bi = n0 + 3; }

    // Wave (64-lane) reduction: larger value wins; equal -> smaller index.
    for (int off = 32; off >= 1; off >>= 1) {
        float ov = __shfl_down(bv, off, 64);
        int   oi = __shfl_down(bi, off, 64);
        if (ov > bv || (ov == bv && oi < bi)) { bv = ov; bi = oi; }
    }
    const int wave = tid >> 6;
    if ((tid & 63) == 0) { sval[wave] = bv; sidx[wave] = bi; }
    __syncthreads();

    if (tid == 0) {
        #pragma unroll
        for (int i = 1; i < NWAVES1; ++i) {
            if (sval[i] > bv || (sval[i] == bv && sidx[i] < bi)) {
                bv = sval[i]; bi = sidx[i];
            }
        }
        partial[blk] = make_float2(bv, __int_as_float(bi));
    }
}

// One block, 256 threads: thread b merges its batch's 4 slice-partials
// (ascending slice order preserves first-occurrence tiebreak) and writes
// the 3 tail outputs.
__global__ __launch_bounds__(256) void finalize_kernel(
    const float2* __restrict__ partial,
    const float* __restrict__ r_target, const float* __restrict__ d_target,
    float* __restrict__ out)
{
    const int b = threadIdx.x;
    float2 p = partial[b * SLICES];
    float bv = p.x;
    int   bi = __float_as_int(p.y);
    #pragma unroll
    for (int s = 1; s < SLICES; ++s) {
        float2 q = partial[b * SLICES + s];
        const int qi = __float_as_int(q.y);
        if (q.x > bv || (q.x == bv && qi < bi)) { bv = q.x; bi = qi; }
    }
    const int r_index = bi >> 6;        // idx // 64  (len_r == 64)
    const int d_index = bi & 63;        // idx % 64   (len_d == 64)
    // Reference assigns float into int tensor: truncation toward zero.
    const float r = (float)(int)r_target[r_index];
    const float d = (float)(int)d_target[d_index];
    const int BN = BATCH * NDIM;
    out[BN + b]             = d;        // second return element: d
    out[BN + BATCH + b]     = r;        // output tuple: r
    out[BN + 2 * BATCH + b] = d;        // output tuple: d
}

extern "C" void kernel_launch(void* const* d_in, const int* in_sizes, int n_in,
                              void* d_out, int out_size, void* d_ws, size_t ws_size,
                              hipStream_t stream) {
    const float* x        = (const float*)d_in[0];  // [B, C, M, N] = [256,8,16,4096]
    const float* W        = (const float*)d_in[1];  // [1, C, M, 1] -> 128 floats, idx c*16+m
    const float* r_target = (const float*)d_in[2];  // [64]
    const float* d_target = (const float*)d_in[3];  // [64]
    float* out = (float*)d_out;
    float2* partial = (float2*)d_ws;                // 1024 * 8 B = 8 KiB

    // A/B: identical outputs, different load flavor. Both get profiled.
    conv_partial_kernel<true ><<<BATCH * SLICES, THREADS1, 0, stream>>>(x, W, out, partial);
    conv_partial_kernel<false><<<BATCH * SLICES, THREADS1, 0, stream>>>(x, W, out, partial);
    finalize_kernel<<<1, 256, 0, stream>>>(partial, r_target, d_target, out);
}

// Round 4
// 689.055 us; speedup vs baseline: 1.1576x; 1.1576x over previous
//
#include <hip/hip_runtime.h>

// Problem constants (from reference):
//   B=256, C=8, M=16, N=4096, R=D=64, CM=C*M=128
//   outputs[b,n] = sum_cm x[b,cm,n] * w[cm]          (512 MiB in, 4 MiB out)
//   idx = argmax_n outputs[b,:]  (first-max tiebreak)
//   r = trunc(r_target[idx/64]); d = trunc(d_target[idx%64])
//   flat out = [outputs (B*N), d (B), r (B), d (B)]
//
// R4: single-variable change vs R2 -- PLAIN loads instead of
// __builtin_nontemporal_load. R3's A/B showed: VGPR=28, FETCH=284MB,
// WRITE=4.1MB (no traffic amplification, no spills), yet every NT-load
// kernel (R0/R1/R2, three different schedules) pinned at ~310us (~1.7TB/s),
// while R3's added plain-load instance cost only ~130us. Theory: the `nt`
// (no-allocate) load path caps HBM read throughput -- it bypasses the
// L2/L3 allocation path that merges/prefetches requests into full DRAM
// bursts. Plain dwordx4 loads restore the normal cached-read path.
// Re-reads across bench iterations don't need the cache, but the LOAD PATH
// does; the 4 MiB out store stays regular (it IS re-read by the checker).

#define BATCH   256
#define NDIM    4096
#define CM      128
#define SLICES  4
#define SLICE_COLS (NDIM / SLICES)      // 1024
#define THREADS1   (SLICE_COLS / 4)     // 256 threads, 4 cols each
#define NWAVES1    (THREADS1 / 64)      // 4
#define GROUP   8
#define NGROUPS (CM / GROUP)            // 16

typedef float v4f __attribute__((ext_vector_type(4)));

__global__ __launch_bounds__(THREADS1) void conv_partial_kernel(
    const float* __restrict__ x, const float* __restrict__ W,
    float* __restrict__ out, float2* __restrict__ partial)
{
    __shared__ float w[CM];
    __shared__ float sval[NWAVES1];
    __shared__ int   sidx[NWAVES1];

    const int blk = blockIdx.x;
    const int b   = blk >> 2;           // / SLICES
    const int s   = blk & (SLICES - 1);
    const int tid = threadIdx.x;

    if (tid < CM) w[tid] = W[tid];
    __syncthreads();

    const int n0 = s * SLICE_COLS + tid * 4;        // this thread's 4 columns
    const float* xp = x + (size_t)b * (CM * NDIM) + n0;

    float acc0 = 0.f, acc1 = 0.f, acc2 = 0.f, acc3 = 0.f;

    // Compact loop: 8 plain dwordx4 loads in flight -> 8 FMA rows.
    // ~32 staging VGPRs, statically indexed, no spill (VGPR=28 measured in R3).
    #pragma unroll 1
    for (int g = 0; g < NGROUPS; ++g) {
        v4f v[GROUP];
        #pragma unroll
        for (int j = 0; j < GROUP; ++j) {
            v[j] = *(const v4f*)(xp + (size_t)(g * GROUP + j) * NDIM);
        }
        #pragma unroll
        for (int j = 0; j < GROUP; ++j) {
            const float wc = w[g * GROUP + j];      // uniform ds_read broadcast
            acc0 += v[j].x * wc;
            acc1 += v[j].y * wc;
            acc2 += v[j].z * wc;
            acc3 += v[j].w * wc;
        }
    }

    *(float4*)(out + (size_t)b * NDIM + n0) = make_float4(acc0, acc1, acc2, acc3);

    // Thread-local argmax (ascending index => first-occurrence tiebreak).
    float bv = acc0; int bi = n0;
    if (acc1 > bv) { bv = acc1; bi = n0 + 1; }
    if (acc2 > bv) { bv = acc2; bi = n0 + 2; }
    if (acc3 > bv) { bv = acc3; bi = n0 + 3; }

    // Wave (64-lane) reduction: larger value wins; equal -> smaller index.
    for (int off = 32; off >= 1; off >>= 1) {
        float ov = __shfl_down(bv, off, 64);
        int   oi = __shfl_down(bi, off, 64);
        if (ov > bv || (ov == bv && oi < bi)) { bv = ov; bi = oi; }
    }
    const int wave = tid >> 6;
    if ((tid & 63) == 0) { sval[wave] = bv; sidx[wave] = bi; }
    __syncthreads();

    if (tid == 0) {
        #pragma unroll
        for (int i = 1; i < NWAVES1; ++i) {
            if (sval[i] > bv || (sval[i] == bv && sidx[i] < bi)) {
                bv = sval[i]; bi = sidx[i];
            }
        }
        partial[blk] = make_float2(bv, __int_as_float(bi));
    }
}

// One block, 256 threads: thread b merges its batch's 4 slice-partials
// (ascending slice order preserves first-occurrence tiebreak) and writes
// the 3 tail outputs.
__global__ __launch_bounds__(256) void finalize_kernel(
    const float2* __restrict__ partial,
    const float* __restrict__ r_target, const float* __restrict__ d_target,
    float* __restrict__ out)
{
    const int b = threadIdx.x;
    float2 p = partial[b * SLICES];
    float bv = p.x;
    int   bi = __float_as_int(p.y);
    #pragma unroll
    for (int s = 1; s < SLICES; ++s) {
        float2 q = partial[b * SLICES + s];
        const int qi = __float_as_int(q.y);
        if (q.x > bv || (q.x == bv && qi < bi)) { bv = q.x; bi = qi; }
    }
    const int r_index = bi >> 6;        // idx // 64  (len_r == 64)
    const int d_index = bi & 63;        // idx % 64   (len_d == 64)
    // Reference assigns float into int tensor: truncation toward zero.
    const float r = (float)(int)r_target[r_index];
    const float d = (float)(int)d_target[d_index];
    const int BN = BATCH * NDIM;
    out[BN + b]             = d;        // second return element: d
    out[BN + BATCH + b]     = r;        // output tuple: r
    out[BN + 2 * BATCH + b] = d;        // output tuple: d
}

extern "C" void kernel_launch(void* const* d_in, const int* in_sizes, int n_in,
                              void* d_out, int out_size, void* d_ws, size_t ws_size,
                              hipStream_t stream) {
    const float* x        = (const float*)d_in[0];  // [B, C, M, N] = [256,8,16,4096]
    const float* W        = (const float*)d_in[1];  // [1, C, M, 1] -> 128 floats, idx c*16+m
    const float* r_target = (const float*)d_in[2];  // [64]
    const float* d_target = (const float*)d_in[3];  // [64]
    float* out = (float*)d_out;
    float2* partial = (float2*)d_ws;                // 1024 * 8 B = 8 KiB

    conv_partial_kernel<<<BATCH * SLICES, THREADS1, 0, stream>>>(x, W, out, partial);
    finalize_kernel<<<1, 256, 0, stream>>>(partial, r_target, d_target, out);
}